// Round 15
// baseline (213.940 us; speedup 1.0000x reference)
//
#include <hip/hip_runtime.h>

#define NN 50000
#define D 128
#define BM 32
#define SL 6250              // NN/8, dst-slice width (fill slicing)
#define CE 1664              // csr LDS cache entries per block

typedef unsigned int uint;
typedef unsigned short ushort;
typedef __attribute__((ext_vector_type(8))) short bf16x8;
typedef __attribute__((ext_vector_type(4))) float f32x4;

static __device__ __forceinline__ ushort f2bf(float f) {
    uint u = __float_as_uint(f);
    u = (u + 0x7FFFu + ((u >> 16) & 1u)) >> 16;   // RNE
    return (ushort)u;
}

// unpack-accumulate 8 bf16 (one uint4) into a[8]
#define ADD8(a, u)                                                  \
    {                                                               \
        a[0] += __uint_as_float((u).x << 16);                       \
        a[1] += __uint_as_float((u).x & 0xFFFF0000u);               \
        a[2] += __uint_as_float((u).y << 16);                       \
        a[3] += __uint_as_float((u).y & 0xFFFF0000u);               \
        a[4] += __uint_as_float((u).z << 16);                       \
        a[5] += __uint_as_float((u).z & 0xFFFF0000u);               \
        a[6] += __uint_as_float((u).w << 16);                       \
        a[7] += __uint_as_float((u).w & 0xFFFF0000u);               \
    }

// swizzled LDS address (ushort units) of 16B-chunk ch of row r
static __device__ __forceinline__ int ladr(int r, int ch) {
    return r * D + (((ch) ^ (r & 7)) << 3);
}

// ---- per-XCD private histograms: 1 pass over dst, copy = blockIdx&7 ----
__global__ __launch_bounds__(256) void k_hist8(const int* __restrict__ dst,
                                               int* __restrict__ hist8, int E) {
    int* h = hist8 + (blockIdx.x & 7) * NN;
    for (int e = blockIdx.x * 256 + (int)threadIdx.x; e < E; e += 1024 * 256)
        atomicAdd(&h[dst[e]], 1);
}

// ---- scan phase A: sum 8 hist copies -> hist, per-block (512) partial sums ----
__global__ __launch_bounds__(256) void k_bsum(const int* __restrict__ hist8,
        int* __restrict__ hist, int* __restrict__ bsum, int n) {
    const int t = threadIdx.x;
    const int i0 = blockIdx.x * 512 + t * 2;
    int s = 0;
    #pragma unroll
    for (int k = 0; k < 2; ++k) {
        const int i = i0 + k;
        if (i < n) {
            int v = 0;
            #pragma unroll
            for (int c = 0; c < 8; ++c) v += hist8[c * NN + i];
            hist[i] = v;
            s += v;
        }
    }
    #pragma unroll
    for (int o = 1; o < 64; o <<= 1) s += __shfl_xor(s, o);
    __shared__ int wsum[4];
    if ((t & 63) == 0) wsum[t >> 6] = s;
    __syncthreads();
    if (t == 0) bsum[blockIdx.x] = wsum[0] + wsum[1] + wsum[2] + wsum[3];
}

// ---- fused dispatch: [scan B+C 98 blocks | cvt 3125 | wpack 256] ----
__global__ __launch_bounds__(256) void k_scanapply_f(
    const int* __restrict__ hist, const int* __restrict__ bsum,
    int* __restrict__ row_off, int* __restrict__ cursor, int n, int E, int nb,
    const float* __restrict__ x, ushort* __restrict__ xb,
    const float* __restrict__ W0, const float* __restrict__ W1,
    const float* __restrict__ W2, const float* __restrict__ W3,
    ushort* __restrict__ P)
{
    const int bid = blockIdx.x;
    const int t = threadIdx.x;
    if (bid < nb) {
        const int sb = bid;
        const int lane = t & 63, w = t >> 6;
        __shared__ int red[4], wsum[4], woff[4], baseS;

        int v = (t < nb && t < sb) ? bsum[t] : 0;
        #pragma unroll
        for (int o = 1; o < 64; o <<= 1) v += __shfl_xor(v, o);
        if (lane == 0) red[w] = v;
        __syncthreads();
        if (t == 0) baseS = red[0] + red[1] + red[2] + red[3];
        __syncthreads();
        const int base = baseS;

        const int i0 = sb * 512 + t * 2;
        const int v0 = (i0 < n) ? hist[i0] : 0;
        const int v1 = (i0 + 1 < n) ? hist[i0 + 1] : 0;
        const int s = v0 + v1;
        int inc = s;
        #pragma unroll
        for (int o = 1; o < 64; o <<= 1) { int u = __shfl_up(inc, o); if (lane >= o) inc += u; }
        if (lane == 63) wsum[w] = inc;
        __syncthreads();
        if (t == 0) { int r = 0; for (int k = 0; k < 4; ++k) { woff[k] = r; r += wsum[k]; } }
        __syncthreads();
        const int ex = base + woff[w] + (inc - s);
        if (i0 < n)     { row_off[i0] = ex;          cursor[i0] = ex; }
        if (i0 + 1 < n) { row_off[i0 + 1] = ex + v0; cursor[i0 + 1] = ex + v0; }
        if (sb == 0 && t == 0) row_off[n] = E;
    } else if (bid < nb + 3125) {
        const int tt = (bid - nb) * 256 + t;
        const float4* p = reinterpret_cast<const float4*>(x) + (size_t)tt * 2;
        const float4 v0 = p[0], v1 = p[1];
        uint4 u;
        u.x = (uint)f2bf(v0.x) | ((uint)f2bf(v0.y) << 16);
        u.y = (uint)f2bf(v0.z) | ((uint)f2bf(v0.w) << 16);
        u.z = (uint)f2bf(v1.x) | ((uint)f2bf(v1.y) << 16);
        u.w = (uint)f2bf(v1.z) | ((uint)f2bf(v1.w) << 16);
        reinterpret_cast<uint4*>(xb)[tt] = u;
    } else {
        const int o = (bid - nb - 3125) * 256 + t;           // < 65536
        const int mat = o >> 14;
        const int idx = o & 16383;
        const int kt = idx >> 12;
        const int nn = (idx >> 5) & 127;
        const int ks = idx & 31;
        const float* W = (mat == 0) ? W0 : (mat == 1) ? W1 : (mat == 2) ? W2 : W3;
        P[o] = f2bf(W[(kt * 32 + ks) * D + nn]);
    }
}

// ---- sliced CSR fill ----
__global__ __launch_bounds__(256) void k_fill_s(const int* __restrict__ src,
        const int* __restrict__ dst, int* __restrict__ cursor,
        int* __restrict__ csr, int E) {
    const int s = blockIdx.x & 7;
    const int lo = s * SL, hi = lo + SL;
    const int bs = blockIdx.x >> 3;
    const int stride = (gridDim.x >> 3) * 256;
    for (int e = bs * 256 + (int)threadIdx.x; e < E; e += stride) {
        const int d = dst[e];
        const int sv = src[e];
        if (d >= lo && d < hi) {
            const int p = atomicAdd(&cursor[d], 1);
            csr[p] = sv;
        }
    }
}

// ---- fused SAGE layer: pull-mean + dual MFMA GEMM + bias + ReLU (+ L2 norm) ----
// BM=32, 512 threads = 8 waves, 4 blocks/CU (LDS-bound). Pull: 16-lane quarter
// per row, csr from LDS broadcast, unroll-8 (8 gathers in flight per lane).
template<bool NORM>
__global__ __launch_bounds__(512, 8) void k_sage(
    const ushort* __restrict__ hb,
    const int* __restrict__ csr, const int* __restrict__ row_off,
    const ushort* __restrict__ Wps, const ushort* __restrict__ Wpn,
    const float* __restrict__ bias, ushort* __restrict__ outb,
    float* __restrict__ out, int n, int E)
{
    __shared__ __align__(16) ushort hsb[BM * D];
    __shared__ __align__(16) ushort hnb[BM * D];
    __shared__ float outt[BM * 132];
    __shared__ int csre[CE];
    const int row0 = blockIdx.x * BM;
    const int tid = threadIdx.x;
    const int l = tid & 63;
    const int w = tid >> 6;

    // ---- stage block csr segment (contiguous range for rows row0..row0+31) ----
    const int rhi = min(row0 + BM, n);
    const int beg0 = row_off[row0];
    const int EB = row_off[rhi] - beg0;
    const bool useLds = (EB <= CE);
    if (useLds) {
        for (int j = tid; j < EB; j += 512) csre[j] = csr[beg0 + j];
    }

    // ---- stage self tile (bf16 copy, swizzled) ----
    {
        const int r = tid >> 4;
        const int ch = tid & 15;
        const int g = row0 + r;
        uint4 u = make_uint4(0u, 0u, 0u, 0u);
        if (g < n) u = *reinterpret_cast<const uint4*>(hb + (size_t)g * D + ch * 8);
        *reinterpret_cast<uint4*>(&hsb[ladr(r, ch)]) = u;
    }
    __syncthreads();   // csre ready for pull

    // ---- pull neighbor mean for row r = tid>>4, channels (tid&15)*8..+8 ----
    {
        const int r = tid >> 4;
        const int ql = tid & 15;
        const int g = row0 + r;
        int i = 0, e = 0;
        if (g < n) { i = row_off[g]; e = row_off[g + 1]; }
        const float invd = (e > i) ? 1.0f / (float)(e - i) : 0.0f;
        float a[8];
        #pragma unroll
        for (int j = 0; j < 8; ++j) a[j] = 0.f;
        const size_t off = (size_t)(ql * 8);
        if (useLds) {
            int li = i - beg0;
            const int le = e - beg0;
            for (; li + 7 < le; li += 8) {
                const int s0 = csre[li],     s1 = csre[li + 1], s2 = csre[li + 2], s3 = csre[li + 3];
                const int s4 = csre[li + 4], s5 = csre[li + 5], s6 = csre[li + 6], s7 = csre[li + 7];
                const uint4 u0 = *reinterpret_cast<const uint4*>(hb + (size_t)s0 * D + off);
                const uint4 u1 = *reinterpret_cast<const uint4*>(hb + (size_t)s1 * D + off);
                const uint4 u2 = *reinterpret_cast<const uint4*>(hb + (size_t)s2 * D + off);
                const uint4 u3 = *reinterpret_cast<const uint4*>(hb + (size_t)s3 * D + off);
                const uint4 u4 = *reinterpret_cast<const uint4*>(hb + (size_t)s4 * D + off);
                const uint4 u5 = *reinterpret_cast<const uint4*>(hb + (size_t)s5 * D + off);
                const uint4 u6 = *reinterpret_cast<const uint4*>(hb + (size_t)s6 * D + off);
                const uint4 u7 = *reinterpret_cast<const uint4*>(hb + (size_t)s7 * D + off);
                ADD8(a, u0); ADD8(a, u1); ADD8(a, u2); ADD8(a, u3);
                ADD8(a, u4); ADD8(a, u5); ADD8(a, u6); ADD8(a, u7);
            }
            for (; li + 3 < le; li += 4) {
                const int s0 = csre[li], s1 = csre[li + 1], s2 = csre[li + 2], s3 = csre[li + 3];
                const uint4 u0 = *reinterpret_cast<const uint4*>(hb + (size_t)s0 * D + off);
                const uint4 u1 = *reinterpret_cast<const uint4*>(hb + (size_t)s1 * D + off);
                const uint4 u2 = *reinterpret_cast<const uint4*>(hb + (size_t)s2 * D + off);
                const uint4 u3 = *reinterpret_cast<const uint4*>(hb + (size_t)s3 * D + off);
                ADD8(a, u0); ADD8(a, u1); ADD8(a, u2); ADD8(a, u3);
            }
            for (; li < le; ++li) {
                const int s0 = csre[li];
                const uint4 u0 = *reinterpret_cast<const uint4*>(hb + (size_t)s0 * D + off);
                ADD8(a, u0);
            }
        } else {
            for (; i + 3 < e; i += 4) {
                const int s0 = csr[i], s1 = csr[i + 1], s2 = csr[i + 2], s3 = csr[i + 3];
                const uint4 u0 = *reinterpret_cast<const uint4*>(hb + (size_t)s0 * D + off);
                const uint4 u1 = *reinterpret_cast<const uint4*>(hb + (size_t)s1 * D + off);
                const uint4 u2 = *reinterpret_cast<const uint4*>(hb + (size_t)s2 * D + off);
                const uint4 u3 = *reinterpret_cast<const uint4*>(hb + (size_t)s3 * D + off);
                ADD8(a, u0); ADD8(a, u1); ADD8(a, u2); ADD8(a, u3);
            }
            for (; i < e; ++i) {
                const int s0 = csr[i];
                const uint4 u0 = *reinterpret_cast<const uint4*>(hb + (size_t)s0 * D + off);
                ADD8(a, u0);
            }
        }
        uint4 u;
        u.x = (uint)f2bf(a[0] * invd) | ((uint)f2bf(a[1] * invd) << 16);
        u.y = (uint)f2bf(a[2] * invd) | ((uint)f2bf(a[3] * invd) << 16);
        u.z = (uint)f2bf(a[4] * invd) | ((uint)f2bf(a[5] * invd) << 16);
        u.w = (uint)f2bf(a[6] * invd) | ((uint)f2bf(a[7] * invd) << 16);
        *reinterpret_cast<uint4*>(&hnb[ladr(r, ql)]) = u;
    }
    __syncthreads();

    // ---- MFMA: wave w -> m-tile (w>>2), n-tiles (w&3)*2, +1 ----
    {
        const int mt = w >> 2;
        const int ntA = (w & 3) * 2;
        const int rA = mt * 16 + (l & 15);
        const int kg = l >> 4;
        f32x4 acc0 = {0.f, 0.f, 0.f, 0.f};
        f32x4 acc1 = {0.f, 0.f, 0.f, 0.f};
        #pragma unroll
        for (int kt = 0; kt < 4; ++kt) {
            const int kc = kt * 4 + kg;
            const bf16x8 as = *reinterpret_cast<const bf16x8*>(&hsb[ladr(rA, kc)]);
            const bf16x8 an = *reinterpret_cast<const bf16x8*>(&hnb[ladr(rA, kc)]);
            const size_t wo0 = (size_t)(kt * 128 + ntA * 16 + (l & 15)) * 32 + kg * 8;
            const size_t wo1 = wo0 + 16 * 32;
            const bf16x8 bs0 = *reinterpret_cast<const bf16x8*>(Wps + wo0);
            const bf16x8 bn0 = *reinterpret_cast<const bf16x8*>(Wpn + wo0);
            const bf16x8 bs1 = *reinterpret_cast<const bf16x8*>(Wps + wo1);
            const bf16x8 bn1 = *reinterpret_cast<const bf16x8*>(Wpn + wo1);
            acc0 = __builtin_amdgcn_mfma_f32_16x16x32_bf16(as, bs0, acc0, 0, 0, 0);
            acc0 = __builtin_amdgcn_mfma_f32_16x16x32_bf16(an, bn0, acc0, 0, 0, 0);
            acc1 = __builtin_amdgcn_mfma_f32_16x16x32_bf16(as, bs1, acc1, 0, 0, 0);
            acc1 = __builtin_amdgcn_mfma_f32_16x16x32_bf16(an, bn1, acc1, 0, 0, 0);
        }
        const int c0 = ntA * 16 + (l & 15);
        const float bv0 = bias[c0], bv1 = bias[c0 + 16];
        #pragma unroll
        for (int i2 = 0; i2 < 4; ++i2) {
            const int rr = mt * 16 + kg * 4 + i2;
            outt[rr * 132 + c0]      = fmaxf(acc0[i2] + bv0, 0.f);
            outt[rr * 132 + c0 + 16] = fmaxf(acc1[i2] + bv1, 0.f);
        }
    }
    __syncthreads();

    // ---- epilogue: row r = tid>>4, channels (tid&15)*8..+8 ----
    {
        const int r = tid >> 4;
        const int c = (tid & 15) * 8;
        const int g = row0 + r;
        float4 v0 = *reinterpret_cast<const float4*>(&outt[r * 132 + c]);
        float4 v1 = *reinterpret_cast<const float4*>(&outt[r * 132 + c + 4]);
        if (!NORM) {
            if (g < n) {
                uint4 u;
                u.x = (uint)f2bf(v0.x) | ((uint)f2bf(v0.y) << 16);
                u.y = (uint)f2bf(v0.z) | ((uint)f2bf(v0.w) << 16);
                u.z = (uint)f2bf(v1.x) | ((uint)f2bf(v1.y) << 16);
                u.w = (uint)f2bf(v1.z) | ((uint)f2bf(v1.w) << 16);
                *reinterpret_cast<uint4*>(outb + (size_t)g * D + c) = u;
            }
        } else {
            float ssq = v0.x * v0.x + v0.y * v0.y + v0.z * v0.z + v0.w * v0.w
                      + v1.x * v1.x + v1.y * v1.y + v1.z * v1.z + v1.w * v1.w;
            #pragma unroll
            for (int o = 1; o < 16; o <<= 1) ssq += __shfl_xor(ssq, o);
            const float scale = 1.0f / fmaxf(sqrtf(ssq), 1e-12f);
            if (g < n) {
                v0.x *= scale; v0.y *= scale; v0.z *= scale; v0.w *= scale;
                v1.x *= scale; v1.y *= scale; v1.z *= scale; v1.w *= scale;
                *reinterpret_cast<float4*>(out + (size_t)g * D + c)     = v0;
                *reinterpret_cast<float4*>(out + (size_t)g * D + c + 4) = v1;
            }
        }
    }
}

extern "C" void kernel_launch(void* const* d_in, const int* in_sizes, int n_in,
                              void* d_out, int out_size, void* d_ws, size_t ws_size,
                              hipStream_t stream) {
    const float* x   = (const float*)d_in[0];
    const int*   src = (const int*)d_in[1];
    const int*   dst = (const int*)d_in[2];
    const float* Ws0 = (const float*)d_in[3];
    const float* Wn0 = (const float*)d_in[4];
    const float* b0  = (const float*)d_in[5];
    const float* Ws1 = (const float*)d_in[6];
    const float* Wn1 = (const float*)d_in[7];
    const float* b1  = (const float*)d_in[8];
    float* out = (float*)d_out;
    const int E = in_sizes[1];

    // workspace layout (~31.2 MB)
    ushort* xb     = (ushort*)d_ws;                      // NN*D bf16 = 12.8 MB
    ushort* h1b    = xb + (size_t)NN * D;                // NN*D bf16 = 12.8 MB
    ushort* Wp     = h1b + (size_t)NN * D;               // 4*16384 bf16 = 128 KB
    int*    hist8  = (int*)(Wp + 65536);                 // 8*NN = 1.6 MB
    int*    hist   = hist8 + 8 * NN;                     // NN
    int*    bsum   = hist + NN;                          // 128
    int*    row_off= bsum + 128;                         // NN+1
    int*    cursor = row_off + NN + 1;                   // NN
    int*    csr    = cursor + NN;                        // E

    ushort* Wps0 = Wp;
    ushort* Wpn0 = Wp + 16384;
    ushort* Wps1 = Wp + 32768;
    ushort* Wpn1 = Wp + 49152;

    const int nb = (NN + 511) / 512;                     // 98 scan blocks

    hipMemsetAsync(hist8, 0, (size_t)8 * NN * sizeof(int), stream);
    k_hist8<<<1024, 256, 0, stream>>>(dst, hist8, E);
    k_bsum<<<nb, 256, 0, stream>>>(hist8, hist, bsum, NN);
    k_scanapply_f<<<nb + 3125 + 256, 256, 0, stream>>>(
        hist, bsum, row_off, cursor, NN, E, nb,
        x, xb, Ws0, Wn0, Ws1, Wn1, Wp);
    k_fill_s<<<1024, 256, 0, stream>>>(src, dst, cursor, csr, E);

    // ---- layer 1: xb -> h1b (bf16) ----
    k_sage<false><<<(NN + BM - 1) / BM, 512, 0, stream>>>(
        xb, csr, row_off, Wps0, Wpn0, b0, h1b, nullptr, NN, E);

    // ---- layer 2 + normalize: h1b -> out (fp32) ----
    k_sage<true><<<(NN + BM - 1) / BM, 512, 0, stream>>>(
        h1b, csr, row_off, Wps1, Wpn1, b1, nullptr, out, NN, E);
}

// Round 16
// 168.013 us; speedup vs baseline: 1.2733x; 1.2733x over previous
//
#include <hip/hip_runtime.h>

#define NN 50000
#define D 128
#define BM 32
#define SL 6250              // NN/8, dst-slice width (fill slicing)
#define CE 1664              // csr LDS cache entries per block

typedef unsigned int uint;
typedef unsigned short ushort;
typedef __attribute__((ext_vector_type(8))) short bf16x8;
typedef __attribute__((ext_vector_type(4))) float f32x4;

static __device__ __forceinline__ ushort f2bf(float f) {
    uint u = __float_as_uint(f);
    u = (u + 0x7FFFu + ((u >> 16) & 1u)) >> 16;   // RNE
    return (ushort)u;
}

// unpack-accumulate 8 bf16 (one uint4) into a[8]
#define ADD8(a, u)                                                  \
    {                                                               \
        a[0] += __uint_as_float((u).x << 16);                       \
        a[1] += __uint_as_float((u).x & 0xFFFF0000u);               \
        a[2] += __uint_as_float((u).y << 16);                       \
        a[3] += __uint_as_float((u).y & 0xFFFF0000u);               \
        a[4] += __uint_as_float((u).z << 16);                       \
        a[5] += __uint_as_float((u).z & 0xFFFF0000u);               \
        a[6] += __uint_as_float((u).w << 16);                       \
        a[7] += __uint_as_float((u).w & 0xFFFF0000u);               \
    }

// swizzled LDS address (ushort units) of 16B-chunk ch of row r
static __device__ __forceinline__ int ladr(int r, int ch) {
    return r * D + (((ch) ^ (r & 7)) << 3);
}

// ---- fused prep A: [per-XCD hist 1024 | cvt 3125 | wpack 256] ----
// all three independent; co-scheduled in one dispatch.
__global__ __launch_bounds__(256) void k_prepA(
    const int* __restrict__ dst, int* __restrict__ hist8, int E,
    const float* __restrict__ x, ushort* __restrict__ xb,
    const float* __restrict__ W0, const float* __restrict__ W1,
    const float* __restrict__ W2, const float* __restrict__ W3,
    ushort* __restrict__ P)
{
    const int bid = blockIdx.x;
    const int t = threadIdx.x;
    if (bid < 1024) {
        // per-XCD private histogram: copy = bid&7, one pass over dst
        int* h = hist8 + (bid & 7) * NN;
        for (int e = bid * 256 + t; e < E; e += 1024 * 256)
            atomicAdd(&h[dst[e]], 1);
    } else if (bid < 1024 + 3125) {
        // fp32 -> bf16 row-major mirror, 8 elems/thread
        const int tt = (bid - 1024) * 256 + t;
        const float4* p = reinterpret_cast<const float4*>(x) + (size_t)tt * 2;
        const float4 v0 = p[0], v1 = p[1];
        uint4 u;
        u.x = (uint)f2bf(v0.x) | ((uint)f2bf(v0.y) << 16);
        u.y = (uint)f2bf(v0.z) | ((uint)f2bf(v0.w) << 16);
        u.z = (uint)f2bf(v1.x) | ((uint)f2bf(v1.y) << 16);
        u.w = (uint)f2bf(v1.z) | ((uint)f2bf(v1.w) << 16);
        reinterpret_cast<uint4*>(xb)[tt] = u;
    } else {
        // pack W (fp32 [k][n]) into fragment-major bf16 P[(kt*128+n)*32+ks]
        const int o = (bid - 1024 - 3125) * 256 + t;         // < 65536
        const int mat = o >> 14;
        const int idx = o & 16383;
        const int kt = idx >> 12;
        const int nn = (idx >> 5) & 127;
        const int ks = idx & 31;
        const float* W = (mat == 0) ? W0 : (mat == 1) ? W1 : (mat == 2) ? W2 : W3;
        P[o] = f2bf(W[(kt * 32 + ks) * D + nn]);
    }
}

// ---- scan phase A: sum 8 hist copies -> hist, per-block (512) partial sums ----
__global__ __launch_bounds__(256) void k_bsum(const int* __restrict__ hist8,
        int* __restrict__ hist, int* __restrict__ bsum, int n) {
    const int t = threadIdx.x;
    const int i0 = blockIdx.x * 512 + t * 2;
    int s = 0;
    #pragma unroll
    for (int k = 0; k < 2; ++k) {
        const int i = i0 + k;
        if (i < n) {
            int v = 0;
            #pragma unroll
            for (int c = 0; c < 8; ++c) v += hist8[c * NN + i];
            hist[i] = v;
            s += v;
        }
    }
    #pragma unroll
    for (int o = 1; o < 64; o <<= 1) s += __shfl_xor(s, o);
    __shared__ int wsum[4];
    if ((t & 63) == 0) wsum[t >> 6] = s;
    __syncthreads();
    if (t == 0) bsum[blockIdx.x] = wsum[0] + wsum[1] + wsum[2] + wsum[3];
}

// ---- scan B+C (98 blocks) ----
__global__ __launch_bounds__(256) void k_scanapply(const int* __restrict__ hist,
        const int* __restrict__ bsum, int* __restrict__ row_off,
        int* __restrict__ cursor, int n, int E, int nb) {
    const int t = threadIdx.x;
    const int lane = t & 63, w = t >> 6;
    __shared__ int red[4], wsum[4], woff[4], baseS;

    int v = (t < nb && t < blockIdx.x) ? bsum[t] : 0;
    #pragma unroll
    for (int o = 1; o < 64; o <<= 1) v += __shfl_xor(v, o);
    if (lane == 0) red[w] = v;
    __syncthreads();
    if (t == 0) baseS = red[0] + red[1] + red[2] + red[3];
    __syncthreads();
    const int base = baseS;

    const int i0 = blockIdx.x * 512 + t * 2;
    const int v0 = (i0 < n) ? hist[i0] : 0;
    const int v1 = (i0 + 1 < n) ? hist[i0 + 1] : 0;
    const int s = v0 + v1;
    int inc = s;
    #pragma unroll
    for (int o = 1; o < 64; o <<= 1) { int u = __shfl_up(inc, o); if (lane >= o) inc += u; }
    if (lane == 63) wsum[w] = inc;
    __syncthreads();
    if (t == 0) { int r = 0; for (int k = 0; k < 4; ++k) { woff[k] = r; r += wsum[k]; } }
    __syncthreads();
    const int ex = base + woff[w] + (inc - s);
    if (i0 < n)     { row_off[i0] = ex;          cursor[i0] = ex; }
    if (i0 + 1 < n) { row_off[i0 + 1] = ex + v0; cursor[i0 + 1] = ex + v0; }
    if (blockIdx.x == 0 && t == 0) row_off[n] = E;
}

// ---- sliced CSR fill ----
__global__ __launch_bounds__(256) void k_fill_s(const int* __restrict__ src,
        const int* __restrict__ dst, int* __restrict__ cursor,
        int* __restrict__ csr, int E) {
    const int s = blockIdx.x & 7;
    const int lo = s * SL, hi = lo + SL;
    const int bs = blockIdx.x >> 3;
    const int stride = (gridDim.x >> 3) * 256;
    for (int e = bs * 256 + (int)threadIdx.x; e < E; e += stride) {
        const int d = dst[e];
        const int sv = src[e];
        if (d >= lo && d < hi) {
            const int p = atomicAdd(&cursor[d], 1);
            csr[p] = sv;
        }
    }
}

// ---- fused SAGE layer: pull-mean + dual MFMA GEMM + bias + ReLU (+ L2 norm) ----
// BM=32, 512 threads = 8 waves, (512,8). Pull: 16-lane quarter per row,
// unroll-4 (R14-proven; unroll-8 spills at this bound — R15), csr from LDS.
template<bool NORM>
__global__ __launch_bounds__(512, 8) void k_sage(
    const ushort* __restrict__ hb,
    const int* __restrict__ csr, const int* __restrict__ row_off,
    const ushort* __restrict__ Wps, const ushort* __restrict__ Wpn,
    const float* __restrict__ bias, ushort* __restrict__ outb,
    float* __restrict__ out, int n, int E)
{
    __shared__ __align__(16) ushort hsb[BM * D];
    __shared__ __align__(16) ushort hnb[BM * D];
    __shared__ float outt[BM * 132];
    __shared__ int csre[CE];
    const int row0 = blockIdx.x * BM;
    const int tid = threadIdx.x;
    const int l = tid & 63;
    const int w = tid >> 6;

    // ---- stage block csr segment (contiguous range for rows row0..row0+31) ----
    const int rhi = min(row0 + BM, n);
    const int beg0 = row_off[row0];
    const int EB = row_off[rhi] - beg0;
    const bool useLds = (EB <= CE);
    if (useLds) {
        for (int j = tid; j < EB; j += 512) csre[j] = csr[beg0 + j];
    }

    // ---- stage self tile (bf16 copy, swizzled) ----
    {
        const int r = tid >> 4;
        const int ch = tid & 15;
        const int g = row0 + r;
        uint4 u = make_uint4(0u, 0u, 0u, 0u);
        if (g < n) u = *reinterpret_cast<const uint4*>(hb + (size_t)g * D + ch * 8);
        *reinterpret_cast<uint4*>(&hsb[ladr(r, ch)]) = u;
    }
    __syncthreads();   // csre ready for pull

    // ---- pull neighbor mean for row r = tid>>4, channels (tid&15)*8..+8 ----
    {
        const int r = tid >> 4;
        const int ql = tid & 15;
        const int g = row0 + r;
        int i = 0, e = 0;
        if (g < n) { i = row_off[g]; e = row_off[g + 1]; }
        const float invd = (e > i) ? 1.0f / (float)(e - i) : 0.0f;
        float a[8];
        #pragma unroll
        for (int j = 0; j < 8; ++j) a[j] = 0.f;
        const size_t off = (size_t)(ql * 8);
        if (useLds) {
            int li = i - beg0;
            const int le = e - beg0;
            for (; li + 3 < le; li += 4) {
                const int s0 = csre[li], s1 = csre[li + 1], s2 = csre[li + 2], s3 = csre[li + 3];
                const uint4 u0 = *reinterpret_cast<const uint4*>(hb + (size_t)s0 * D + off);
                const uint4 u1 = *reinterpret_cast<const uint4*>(hb + (size_t)s1 * D + off);
                const uint4 u2 = *reinterpret_cast<const uint4*>(hb + (size_t)s2 * D + off);
                const uint4 u3 = *reinterpret_cast<const uint4*>(hb + (size_t)s3 * D + off);
                ADD8(a, u0); ADD8(a, u1); ADD8(a, u2); ADD8(a, u3);
            }
            for (; li < le; ++li) {
                const int s0 = csre[li];
                const uint4 u0 = *reinterpret_cast<const uint4*>(hb + (size_t)s0 * D + off);
                ADD8(a, u0);
            }
        } else {
            for (; i + 3 < e; i += 4) {
                const int s0 = csr[i], s1 = csr[i + 1], s2 = csr[i + 2], s3 = csr[i + 3];
                const uint4 u0 = *reinterpret_cast<const uint4*>(hb + (size_t)s0 * D + off);
                const uint4 u1 = *reinterpret_cast<const uint4*>(hb + (size_t)s1 * D + off);
                const uint4 u2 = *reinterpret_cast<const uint4*>(hb + (size_t)s2 * D + off);
                const uint4 u3 = *reinterpret_cast<const uint4*>(hb + (size_t)s3 * D + off);
                ADD8(a, u0); ADD8(a, u1); ADD8(a, u2); ADD8(a, u3);
            }
            for (; i < e; ++i) {
                const int s0 = csr[i];
                const uint4 u0 = *reinterpret_cast<const uint4*>(hb + (size_t)s0 * D + off);
                ADD8(a, u0);
            }
        }
        uint4 u;
        u.x = (uint)f2bf(a[0] * invd) | ((uint)f2bf(a[1] * invd) << 16);
        u.y = (uint)f2bf(a[2] * invd) | ((uint)f2bf(a[3] * invd) << 16);
        u.z = (uint)f2bf(a[4] * invd) | ((uint)f2bf(a[5] * invd) << 16);
        u.w = (uint)f2bf(a[6] * invd) | ((uint)f2bf(a[7] * invd) << 16);
        *reinterpret_cast<uint4*>(&hnb[ladr(r, ql)]) = u;
    }
    __syncthreads();

    // ---- MFMA: wave w -> m-tile (w>>2), n-tiles (w&3)*2, +1 ----
    {
        const int mt = w >> 2;
        const int ntA = (w & 3) * 2;
        const int rA = mt * 16 + (l & 15);
        const int kg = l >> 4;
        f32x4 acc0 = {0.f, 0.f, 0.f, 0.f};
        f32x4 acc1 = {0.f, 0.f, 0.f, 0.f};
        #pragma unroll
        for (int kt = 0; kt < 4; ++kt) {
            const int kc = kt * 4 + kg;
            const bf16x8 as = *reinterpret_cast<const bf16x8*>(&hsb[ladr(rA, kc)]);
            const bf16x8 an = *reinterpret_cast<const bf16x8*>(&hnb[ladr(rA, kc)]);
            const size_t wo0 = (size_t)(kt * 128 + ntA * 16 + (l & 15)) * 32 + kg * 8;
            const size_t wo1 = wo0 + 16 * 32;
            const bf16x8 bs0 = *reinterpret_cast<const bf16x8*>(Wps + wo0);
            const bf16x8 bn0 = *reinterpret_cast<const bf16x8*>(Wpn + wo0);
            const bf16x8 bs1 = *reinterpret_cast<const bf16x8*>(Wps + wo1);
            const bf16x8 bn1 = *reinterpret_cast<const bf16x8*>(Wpn + wo1);
            acc0 = __builtin_amdgcn_mfma_f32_16x16x32_bf16(as, bs0, acc0, 0, 0, 0);
            acc0 = __builtin_amdgcn_mfma_f32_16x16x32_bf16(an, bn0, acc0, 0, 0, 0);
            acc1 = __builtin_amdgcn_mfma_f32_16x16x32_bf16(as, bs1, acc1, 0, 0, 0);
            acc1 = __builtin_amdgcn_mfma_f32_16x16x32_bf16(an, bn1, acc1, 0, 0, 0);
        }
        const int c0 = ntA * 16 + (l & 15);
        const float bv0 = bias[c0], bv1 = bias[c0 + 16];
        #pragma unroll
        for (int i2 = 0; i2 < 4; ++i2) {
            const int rr = mt * 16 + kg * 4 + i2;
            outt[rr * 132 + c0]      = fmaxf(acc0[i2] + bv0, 0.f);
            outt[rr * 132 + c0 + 16] = fmaxf(acc1[i2] + bv1, 0.f);
        }
    }
    __syncthreads();

    // ---- epilogue: row r = tid>>4, channels (tid&15)*8..+8 ----
    {
        const int r = tid >> 4;
        const int c = (tid & 15) * 8;
        const int g = row0 + r;
        float4 v0 = *reinterpret_cast<const float4*>(&outt[r * 132 + c]);
        float4 v1 = *reinterpret_cast<const float4*>(&outt[r * 132 + c + 4]);
        if (!NORM) {
            if (g < n) {
                uint4 u;
                u.x = (uint)f2bf(v0.x) | ((uint)f2bf(v0.y) << 16);
                u.y = (uint)f2bf(v0.z) | ((uint)f2bf(v0.w) << 16);
                u.z = (uint)f2bf(v1.x) | ((uint)f2bf(v1.y) << 16);
                u.w = (uint)f2bf(v1.z) | ((uint)f2bf(v1.w) << 16);
                *reinterpret_cast<uint4*>(outb + (size_t)g * D + c) = u;
            }
        } else {
            float ssq = v0.x * v0.x + v0.y * v0.y + v0.z * v0.z + v0.w * v0.w
                      + v1.x * v1.x + v1.y * v1.y + v1.z * v1.z + v1.w * v1.w;
            #pragma unroll
            for (int o = 1; o < 16; o <<= 1) ssq += __shfl_xor(ssq, o);
            const float scale = 1.0f / fmaxf(sqrtf(ssq), 1e-12f);
            if (g < n) {
                v0.x *= scale; v0.y *= scale; v0.z *= scale; v0.w *= scale;
                v1.x *= scale; v1.y *= scale; v1.z *= scale; v1.w *= scale;
                *reinterpret_cast<float4*>(out + (size_t)g * D + c)     = v0;
                *reinterpret_cast<float4*>(out + (size_t)g * D + c + 4) = v1;
            }
        }
    }
}

extern "C" void kernel_launch(void* const* d_in, const int* in_sizes, int n_in,
                              void* d_out, int out_size, void* d_ws, size_t ws_size,
                              hipStream_t stream) {
    const float* x   = (const float*)d_in[0];
    const int*   src = (const int*)d_in[1];
    const int*   dst = (const int*)d_in[2];
    const float* Ws0 = (const float*)d_in[3];
    const float* Wn0 = (const float*)d_in[4];
    const float* b0  = (const float*)d_in[5];
    const float* Ws1 = (const float*)d_in[6];
    const float* Wn1 = (const float*)d_in[7];
    const float* b1  = (const float*)d_in[8];
    float* out = (float*)d_out;
    const int E = in_sizes[1];

    // workspace layout (~31.2 MB)
    ushort* xb     = (ushort*)d_ws;                      // NN*D bf16 = 12.8 MB
    ushort* h1b    = xb + (size_t)NN * D;                // NN*D bf16 = 12.8 MB
    ushort* Wp     = h1b + (size_t)NN * D;               // 4*16384 bf16 = 128 KB
    int*    hist8  = (int*)(Wp + 65536);                 // 8*NN = 1.6 MB
    int*    hist   = hist8 + 8 * NN;                     // NN
    int*    bsum   = hist + NN;                          // 128
    int*    row_off= bsum + 128;                         // NN+1
    int*    cursor = row_off + NN + 1;                   // NN
    int*    csr    = cursor + NN;                        // E

    ushort* Wps0 = Wp;
    ushort* Wpn0 = Wp + 16384;
    ushort* Wps1 = Wp + 32768;
    ushort* Wpn1 = Wp + 49152;

    const int nb = (NN + 511) / 512;                     // 98 scan blocks

    hipMemsetAsync(hist8, 0, (size_t)8 * NN * sizeof(int), stream);
    // hist (1024 blocks) co-scheduled with cvt (3125) and wpack (256)
    k_prepA<<<1024 + 3125 + 256, 256, 0, stream>>>(
        dst, hist8, E, x, xb, Ws0, Wn0, Ws1, Wn1, Wp);
    k_bsum<<<nb, 256, 0, stream>>>(hist8, hist, bsum, NN);
    k_scanapply<<<nb, 256, 0, stream>>>(hist, bsum, row_off, cursor, NN, E, nb);
    k_fill_s<<<1024, 256, 0, stream>>>(src, dst, cursor, csr, E);

    // ---- layer 1: xb -> h1b (bf16) ----
    k_sage<false><<<(NN + BM - 1) / BM, 512, 0, stream>>>(
        xb, csr, row_off, Wps0, Wpn0, b0, h1b, nullptr, NN, E);

    // ---- layer 2 + normalize: h1b -> out (fp32) ----
    k_sage<true><<<(NN + BM - 1) / BM, 512, 0, stream>>>(
        h1b, csr, row_off, Wps1, Wpn1, b1, nullptr, out, NN, E);
}